// Round 17
// baseline (1709.871 us; speedup 1.0000x reference)
//
#include <hip/hip_runtime.h>

// ---------------------------------------------------------------------------
// Llama decoder layer, MI355X (gfx950).
// B=2 S=2048 HIDDEN=4096 HQ=32 HKV=8 D=128 INTER=11008, fp32 in/out.
// R17: rmsnorm2 -> 512-thread body (verbatim copy of pre_kernel's audited
// rmsnorm branch as standalone rmsnorm512_kernel). Everything else
// byte-identical to R16. Graph is fully packed: all weight transposes
// hidden (pre/qkv/attn/gate launches), SwiGLU fused, h1 in d_out.
// Overlay lifetimes (audited, unchanged from R16):
//  A: qkvb(s3-s4) | W3(s5-s9) | act(s10-s12)
//  B: tab(s1-s4) | W4(s5-s10)
//  D: W1(s1-s3) | Qr/Kr/Vt(s4-s5) | gate(s9-s10)
//  C: W2(s3-s7) | W5(s9-s12)
//  E: xn(s1-s3) | attnb(s5-s7) | xn(s8-s10)
// ---------------------------------------------------------------------------

typedef __attribute__((ext_vector_type(8))) short bf16x8;
typedef __attribute__((ext_vector_type(4))) float f32x4;

__device__ __forceinline__ ushort f2bf(float f) {           // RNE fp32->bf16
  unsigned u = __float_as_uint(f);
  return (ushort)((u + 0x7fffu + ((u >> 16) & 1u)) >> 16);
}
__device__ __forceinline__ float bf2f(ushort u) {
  union { unsigned u32; float f; } x; x.u32 = ((unsigned)u) << 16; return x.f;
}
__device__ __forceinline__ void gload16(const void* g, void* l) {
  __builtin_amdgcn_global_load_lds((__attribute__((address_space(1))) void*)g,
                                   (__attribute__((address_space(3))) void*)l,
                                   16, 0, 0);
}

#define BARRIER() asm volatile("s_barrier" ::: "memory")
#define WAIT_LGKM0() asm volatile("s_waitcnt lgkmcnt(0)" ::: "memory")
#define WAIT_VM4() asm volatile("s_waitcnt vmcnt(4)" ::: "memory")
#define WAIT_VM0() asm volatile("s_waitcnt vmcnt(0)" ::: "memory")

// ------------------ RMSNorm (fp32 -> bf16), 512 threads --------------------
// Verbatim copy of pre_kernel's rmsnorm branch (R15-audited).
__global__ __launch_bounds__(512) void rmsnorm512_kernel(
    const float* __restrict__ x, const float* __restrict__ g,
    ushort* __restrict__ out) {
  __shared__ float redf[8];
  const int row = blockIdx.x, t = threadIdx.x;
  const float4* xp = (const float4*)(x + (size_t)row * 4096);
  float4 v0 = xp[t], v1 = xp[t + 512];
  float ss = v0.x * v0.x + v0.y * v0.y + v0.z * v0.z + v0.w * v0.w +
             v1.x * v1.x + v1.y * v1.y + v1.z * v1.z + v1.w * v1.w;
#pragma unroll
  for (int m = 32; m; m >>= 1) ss += __shfl_xor(ss, m);
  if ((t & 63) == 0) redf[t >> 6] = ss;
  __syncthreads();
  float tot = redf[0] + redf[1] + redf[2] + redf[3] +
              redf[4] + redf[5] + redf[6] + redf[7];
  float inv = rsqrtf(tot * (1.f / 4096.f) + 1e-6f);
  const float4* gp = (const float4*)g;
  float4 g0 = gp[t], g1 = gp[t + 512];
  ushort* op = out + (size_t)row * 4096;
  ushort4 o0, o1;
  o0.x = f2bf(v0.x * inv * g0.x); o0.y = f2bf(v0.y * inv * g0.y);
  o0.z = f2bf(v0.z * inv * g0.z); o0.w = f2bf(v0.w * inv * g0.w);
  o1.x = f2bf(v1.x * inv * g1.x); o1.y = f2bf(v1.y * inv * g1.y);
  o1.z = f2bf(v1.z * inv * g1.z); o1.w = f2bf(v1.w * inv * g1.w);
  *(ushort4*)(op + (size_t)t * 4) = o0;
  *(ushort4*)(op + (size_t)(t + 512) * 4) = o1;
}

// ------- 512-thread transpose helper (2 x 64x64 tiles per block) -----------
__device__ __forceinline__ void transpose512(
    const float* __restrict__ in, ushort* __restrict__ out,
    int ld_in, int col_off, int R, int ntx, int tbid, ushort* ldsb, int t) {
  const int half = t >> 8, tt = t & 255;
  ushort* tile = ldsb + half * (64 * 65);
  const int x = tbid % ntx, yy = tbid / ntx;
  const int r0 = x * 64, c0 = (yy * 2 + half) * 64;
  const int rl = tt >> 2, cl = (tt & 3) * 16;
  const float* ip = in + (size_t)(r0 + rl) * ld_in + col_off + c0 + cl;
#pragma unroll
  for (int i = 0; i < 4; ++i) {
    float4 f = ((const float4*)ip)[i];
    tile[rl * 65 + cl + i * 4 + 0] = f2bf(f.x);
    tile[rl * 65 + cl + i * 4 + 1] = f2bf(f.y);
    tile[rl * 65 + cl + i * 4 + 2] = f2bf(f.z);
    tile[rl * 65 + cl + i * 4 + 3] = f2bf(f.w);
  }
  __syncthreads();
  union { ushort us[8]; uint4 v; } pk0, pk1;
#pragma unroll
  for (int j = 0; j < 8; ++j) pk0.us[j] = tile[(cl + j) * 65 + rl];
#pragma unroll
  for (int j = 0; j < 8; ++j) pk1.us[j] = tile[(cl + 8 + j) * 65 + rl];
  uint4* op = (uint4*)(out + (size_t)(c0 + rl) * R + r0 + cl);
  op[0] = pk0.v; op[1] = pk1.v;
}

// ---- fused front: rmsnorm1 + w_qkv transpose + rope table (independent) ---
__global__ __launch_bounds__(512) void pre_kernel(
    const float* __restrict__ hs, const float* __restrict__ ln1,
    ushort* __restrict__ xn, const float* __restrict__ wq,
    ushort* __restrict__ W1, const int* __restrict__ pos,
    float2* __restrict__ tab) {
  __shared__ ushort sm[2 * 64 * 65];
  const int bid = (int)blockIdx.x, t = threadIdx.x;
  if (bid < 4096) {              // rmsnorm row = bid, 8 floats/thread
    const float4* xp = (const float4*)(hs + (size_t)bid * 4096);
    float4 v0 = xp[t], v1 = xp[t + 512];
    float ss = v0.x * v0.x + v0.y * v0.y + v0.z * v0.z + v0.w * v0.w +
               v1.x * v1.x + v1.y * v1.y + v1.z * v1.z + v1.w * v1.w;
#pragma unroll
    for (int m = 32; m; m >>= 1) ss += __shfl_xor(ss, m);
    float* redf = (float*)sm;
    if ((t & 63) == 0) redf[t >> 6] = ss;
    __syncthreads();
    float tot = redf[0] + redf[1] + redf[2] + redf[3] +
                redf[4] + redf[5] + redf[6] + redf[7];
    float inv = rsqrtf(tot * (1.f / 4096.f) + 1e-6f);
    const float4* gp = (const float4*)ln1;
    float4 g0 = gp[t], g1 = gp[t + 512];
    ushort* op = xn + (size_t)bid * 4096;
    ushort4 o0, o1;
    o0.x = f2bf(v0.x * inv * g0.x); o0.y = f2bf(v0.y * inv * g0.y);
    o0.z = f2bf(v0.z * inv * g0.z); o0.w = f2bf(v0.w * inv * g0.w);
    o1.x = f2bf(v1.x * inv * g1.x); o1.y = f2bf(v1.y * inv * g1.y);
    o1.z = f2bf(v1.z * inv * g1.z); o1.w = f2bf(v1.w * inv * g1.w);
    *(ushort4*)(op + (size_t)t * 4) = o0;
    *(ushort4*)(op + (size_t)(t + 512) * 4) = o1;
  } else if (bid < 4096 + 3072) {  // w_qkv[4096,6144] -> W1[6144,4096]
    transpose512(wq, W1, 6144, 0, 4096, 64, bid - 4096, sm, t);
  } else {                          // rope table, idx over 2048*64
    int idx = (bid - 7168) * 512 + t;
    int s = idx >> 6, fi = idx & 63;
    float inv = (float)exp(-(double)(2 * fi) / 128.0 * 9.210340371976184);
    float a = (float)pos[s] * inv;
    tab[idx] = make_float2(cosf(a), sinf(a));
  }
}

// ------------------------- GEMM 256x256 8-phase ----------------------------
// Byte-identical to R8..R16 (R4 body + col-major XCD chunk mapping).
template <typename OutT, bool RES>
__global__ __launch_bounds__(512, 2) void gemm256_kernel(
    const ushort* __restrict__ A, const ushort* __restrict__ Bt,
    OutT* __restrict__ C, const float* __restrict__ res,
    int M, int N, int K) {
  extern __shared__ ushort lds[];
  ushort* Al = lds;            // [buf:2][half:2][8192 ushorts]
  ushort* Bl = lds + 32768;
  const int t = threadIdx.x, l = t & 63, w = t >> 6;
  const int wr = w >> 2, wc = w & 3;
  const int lr = l & 15, lg = l >> 4;
  const int rhi = lr >> 3, rlo = lr & 7;
  const int srow = l >> 3, sg = (l & 7) ^ srow;

  const int nby = M >> 8;
  const int nwg = (N >> 8) * nby;
  const int cpx = nwg >> 3;
  const int bid = (int)blockIdx.x;
  const int swz = (bid & 7) * cpx + (bid >> 3);   // XCD chunk (nwg%8==0)
  const int m0 = (swz % nby) << 8;                // col-major: B panel shared
  const int n0 = (swz / nby) << 8;                // by 16 consecutive blocks

  const int lof0 = rhi * 512 + rlo * 64 + ((0 + lg) ^ rlo) * 8;  // kk=0
  const int lof1 = rhi * 512 + rlo * 64 + ((4 + lg) ^ rlo) * 8;  // kk=1

  const f32x4 fz = {0.f, 0.f, 0.f, 0.f};
  f32x4 acc[8][4];
#pragma unroll
  for (int i = 0; i < 8; ++i)
#pragma unroll
    for (int j = 0; j < 4; ++j) acc[i][j] = fz;
  bf16x8 a[8][2];
  bf16x8 bq[2][2];

  const ushort* Asrc = A + (size_t)(m0 + w * 8 + srow) * K + sg * 8;
  const ushort* Bsrc = Bt + (size_t)(n0 + w * 8 + srow) * K + sg * 8;
  const size_t rK64 = (size_t)64 * K, rK128 = (size_t)128 * K;
  ushort* Adst = Al + w * 512;
  ushort* Bdst = Bl + w * 512;

#define STAGE_A(buf, half, tile) do {                                   \
    const ushort* s_ = Asrc + (size_t)(half) * rK128 + ((tile) << 6);   \
    ushort* d_ = Adst + (buf) * 16384 + (half) * 8192;                  \
    gload16(s_, d_);                                                    \
    gload16(s_ + rK64, d_ + 4096);                                      \
  } while (0)
#define STAGE_B(buf, half, tile) do {                                   \
    const ushort* s_ = Bsrc + (size_t)(half) * rK128 + ((tile) << 6);   \
    ushort* d_ = Bdst + (buf) * 16384 + (half) * 8192;                  \
    gload16(s_, d_);                                                    \
    gload16(s_ + rK64, d_ + 4096);                                      \
  } while (0)
#define LDA4(AH, QM) do {                                                   \
    _Pragma("unroll") for (int mi_ = 0; mi_ < 4; ++mi_) {                   \
      a[(QM) * 4 + mi_][0] =                                                \
          *(const bf16x8*)((AH) + ((QM) * 4 + mi_) * 1024 + lof0);          \
      a[(QM) * 4 + mi_][1] =                                                \
          *(const bf16x8*)((AH) + ((QM) * 4 + mi_) * 1024 + lof1);          \
    } } while (0)
#define LDB2(BH, NQ) do {                                                   \
    _Pragma("unroll") for (int nj_ = 0; nj_ < 2; ++nj_) {                   \
      bq[nj_][0] = *(const bf16x8*)((BH) + ((NQ) * 2 + nj_) * 1024 + lof0); \
      bq[nj_][1] = *(const bf16x8*)((BH) + ((NQ) * 2 + nj_) * 1024 + lof1); \
    } } while (0)
#define MFMA16(QM, QN)                                                      \
    __builtin_amdgcn_s_setprio(1);                                          \
    _Pragma("unroll") for (int mi_ = 0; mi_ < 4; ++mi_)                     \
    _Pragma("unroll") for (int nj_ = 0; nj_ < 2; ++nj_) {                   \
      acc[(QM) * 4 + mi_][(QN) * 2 + nj_] =                                 \
          __builtin_amdgcn_mfma_f32_16x16x32_bf16(                          \
              a[(QM) * 4 + mi_][0], bq[nj_][0],                             \
              acc[(QM) * 4 + mi_][(QN) * 2 + nj_], 0, 0, 0);                \
      acc[(QM) * 4 + mi_][(QN) * 2 + nj_] =                                 \
          __builtin_amdgcn_mfma_f32_16x16x32_bf16(                          \
              a[(QM) * 4 + mi_][1], bq[nj_][1],                             \
              acc[(QM) * 4 + mi_][(QN) * 2 + nj_], 0, 0, 0);                \
    }                                                                       \
    __builtin_amdgcn_s_setprio(0);

  const ushort* A0h = Al + wr * 8192;
  const ushort* A1h = A0h + 16384;
  const ushort* B0h = Bl + (wc >> 1) * 8192 + (wc & 1) * 4096;
  const ushort* B1h = B0h + 16384;

  const int ntiles = K >> 6, nIter = K >> 7;
  // prologue: tile0 full -> buf0; tile1 A halves -> buf1
  STAGE_A(0, 0, 0); STAGE_A(0, 1, 0); STAGE_B(0, 0, 0); STAGE_B(0, 1, 0);
  STAGE_A(1, 0, 1); STAGE_A(1, 1, 1);
  WAIT_VM4(); BARRIER();

  for (int it = 0; it < nIter; ++it) {
    const int u = it * 2;
    // ---- tile u (buf0) ----
    LDA4(A0h, 0); LDB2(B0h, 0);                 // P1
    STAGE_B(1, 0, u + 1);
    BARRIER(); WAIT_LGKM0(); MFMA16(0, 0); BARRIER();
    LDA4(A0h, 1);                               // P2
    STAGE_B(1, 1, u + 1);
    BARRIER(); WAIT_LGKM0(); MFMA16(1, 0); BARRIER();
    LDB2(B0h, 1);                               // P3
    if (u + 2 < ntiles) STAGE_A(0, 0, u + 2);
    BARRIER(); WAIT_LGKM0(); MFMA16(0, 1); BARRIER();
    if (u + 2 < ntiles) STAGE_A(0, 1, u + 2);   // P4
    BARRIER(); MFMA16(1, 1);
    if (u + 2 < ntiles) { WAIT_VM4(); } else { WAIT_VM0(); }
    BARRIER();
    // ---- tile u+1 (buf1) ----
    LDA4(A1h, 0); LDB2(B1h, 0);                 // P5
    if (u + 2 < ntiles) STAGE_B(0, 0, u + 2);
    BARRIER(); WAIT_LGKM0(); MFMA16(0, 0); BARRIER();
    LDA4(A1h, 1);                               // P6
    if (u + 2 < ntiles) STAGE_B(0, 1, u + 2);
    BARRIER(); WAIT_LGKM0(); MFMA16(1, 0); BARRIER();
    LDB2(B1h, 1);                               // P7
    if (u + 3 < ntiles) STAGE_A(1, 0, u + 3);
    BARRIER(); WAIT_LGKM0(); MFMA16(0, 1); BARRIER();
    if (u + 3 < ntiles) STAGE_A(1, 1, u + 3);   // P8
    BARRIER(); MFMA16(1, 1);
    WAIT_VM4(); BARRIER();
  }

  // epilogue: C row = m0+wr*128+mi*16+lg*4+r, col = n0+wc*64+ni*16+lr
#pragma unroll
  for (int mi = 0; mi < 8; ++mi)
#pragma unroll
    for (int ni = 0; ni < 4; ++ni)
#pragma unroll
      for (int r = 0; r < 4; ++r) {
        int row = m0 + wr * 128 + mi * 16 + lg * 4 + r;
        int col = n0 + wc * 64 + ni * 16 + lr;
        size_t idx = (size_t)row * N + col;
        float v = acc[mi][ni][r];
        if (RES) v += res[idx];
        if constexpr (sizeof(OutT) == 2) C[idx] = f2bf(v);
        else                             C[idx] = v;
      }
#undef STAGE_A
#undef STAGE_B
#undef LDA4
#undef LDB2
#undef MFMA16
}

// ----------- GEMM (bf16 out, no res) + hidden transpose tail ---------------
// Byte-identical to R14..R16. Used for gate(+w_down) AND qkv(+w_o).
__global__ __launch_bounds__(512, 2) void gemm256_tc_kernel(
    const ushort* __restrict__ A, const ushort* __restrict__ Bt,
    ushort* __restrict__ C, int M, int N, int K,
    const float* tin, ushort* tout, int tld, int toff, int tR, int tntx) {
  extern __shared__ ushort lds[];
  const int nby = M >> 8;
  const int nwg = (N >> 8) * nby;
  const int bid = (int)blockIdx.x;
  const int t = threadIdx.x;
  if (bid >= nwg) {                        // transpose tail blocks
    transpose512(tin, tout, tld, toff, tR, tntx, bid - nwg, lds, t);
    return;
  }
  ushort* Al = lds;
  ushort* Bl = lds + 32768;
  const int l = t & 63, w = t >> 6;
  const int wr = w >> 2, wc = w & 3;
  const int lr = l & 15, lg = l >> 4;
  const int rhi = lr >> 3, rlo = lr & 7;
  const int srow = l >> 3, sg = (l & 7) ^ srow;

  const int cpx = nwg >> 3;
  const int swz = (bid & 7) * cpx + (bid >> 3);
  const int m0 = (swz % nby) << 8;
  const int n0 = (swz / nby) << 8;

  const int lof0 = rhi * 512 + rlo * 64 + ((0 + lg) ^ rlo) * 8;
  const int lof1 = rhi * 512 + rlo * 64 + ((4 + lg) ^ rlo) * 8;

  const f32x4 fz = {0.f, 0.f, 0.f, 0.f};
  f32x4 acc[8][4];
#pragma unroll
  for (int i = 0; i < 8; ++i)
#pragma unroll
    for (int j = 0; j < 4; ++j) acc[i][j] = fz;
  bf16x8 a[8][2];
  bf16x8 bq[2][2];

  const ushort* Asrc = A + (size_t)(m0 + w * 8 + srow) * K + sg * 8;
  const ushort* Bsrc = Bt + (size_t)(n0 + w * 8 + srow) * K + sg * 8;
  const size_t rK64 = (size_t)64 * K, rK128 = (size_t)128 * K;
  ushort* Adst = Al + w * 512;
  ushort* Bdst = Bl + w * 512;

#define STAGE_A(buf, half, tile) do {                                   \
    const ushort* s_ = Asrc + (size_t)(half) * rK128 + ((tile) << 6);   \
    ushort* d_ = Adst + (buf) * 16384 + (half) * 8192;                  \
    gload16(s_, d_);                                                    \
    gload16(s_ + rK64, d_ + 4096);                                      \
  } while (0)
#define STAGE_B(buf, half, tile) do {                                   \
    const ushort* s_ = Bsrc + (size_t)(half) * rK128 + ((tile) << 6);   \
    ushort* d_ = Bdst + (buf) * 16384 + (half) * 8192;                  \
    gload16(s_, d_);                                                    \
    gload16(s_ + rK64, d_ + 4096);                                      \
  } while (0)
#define LDA4(AH, QM) do {                                                   \
    _Pragma("unroll") for (int mi_ = 0; mi_ < 4; ++mi_) {                   \
      a[(QM) * 4 + mi_][0] =                                                \
          *(const bf16x8*)((AH) + ((QM) * 4 + mi_) * 1024 + lof0);          \
      a[(QM) * 4 + mi_][1] =                                                \
          *(const bf16x8*)((AH) + ((QM) * 4 + mi_) * 1024 + lof1);          \
    } } while (0)
#define LDB2(BH, NQ) do {                                                   \
    _Pragma("unroll") for (int nj_ = 0; nj_ < 2; ++nj_) {                   \
      bq[nj_][0] = *(const bf16x8*)((BH) + ((NQ) * 2 + nj_) * 1024 + lof0); \
      bq[nj_][1] = *(const bf16x8*)((BH) + ((NQ) * 2 + nj_) * 1024 + lof1); \
    } } while (0)
#define MFMA16(QM, QN)                                                      \
    __builtin_amdgcn_s_setprio(1);                                          \
    _Pragma("unroll") for (int mi_ = 0; mi_ < 4; ++mi_)                     \
    _Pragma("unroll") for (int nj_ = 0; nj_ < 2; ++nj_) {                   \
      acc[(QM) * 4 + mi_][(QN) * 2 + nj_] =                                 \
          __builtin_amdgcn_mfma_f32_16x16x32_bf16(                          \
              a[(QM) * 4 + mi_][0], bq[nj_][0],                             \
              acc[(QM) * 4 + mi_][(QN) * 2 + nj_], 0, 0, 0);                \
      acc[(QM) * 4 + mi_][(QN) * 2 + nj_] =                                 \
          __builtin_amdgcn_mfma_f32_16x16x32_bf16(                          \
              a[(QM) * 4 + mi_][1], bq[nj_][1],                             \
              acc[(QM) * 4 + mi_][(QN) * 2 + nj_], 0, 0, 0);                \
    }                                                                       \
    __builtin_amdgcn_s_setprio(0);

  const ushort* A0h = Al + wr * 8192;
  const ushort* A1h = A0h + 16384;
  const ushort* B0h = Bl + (wc >> 1) * 8192 + (wc & 1) * 4096;
  const ushort* B1h = B0h + 16384;

  const int ntiles = K >> 6, nIter = K >> 7;
  STAGE_A(0, 0, 0); STAGE_A(0, 1, 0); STAGE_B(0, 0, 0); STAGE_B(0, 1, 0);
  STAGE_A(1, 0, 1); STAGE_A(1, 1, 1);
  WAIT_VM4(); BARRIER();

  for (int it = 0; it < nIter; ++it) {
    const int u = it * 2;
    LDA4(A0h, 0); LDB2(B0h, 0);
    STAGE_B(1, 0, u + 1);
    BARRIER(); WAIT_LGKM0(); MFMA16(0, 0); BARRIER();
    LDA4(A0h, 1);
    STAGE_B(1, 1, u + 1);
    BARRIER(); WAIT_LGKM0(); MFMA16(1, 0); BARRIER();
    LDB2(B0h, 1);
    if (u + 2 < ntiles) STAGE_A(0, 0, u + 2);
    BARRIER(); WAIT_LGKM0(); MFMA16(0, 1); BARRIER();
    if (u + 2 < ntiles) STAGE_A(0, 1, u + 2);
    BARRIER(); MFMA16(1, 1);
    if (u + 2 < ntiles) { WAIT_VM4(); } else { WAIT_VM0(); }
    BARRIER();
    LDA4(A1h, 0); LDB2(B1h, 0);
    if (u + 2 < ntiles) STAGE_B(0, 0, u + 2);
    BARRIER(); WAIT_LGKM0(); MFMA16(0, 0); BARRIER();
    LDA4(A1h, 1);
    if (u + 2 < ntiles) STAGE_B(0, 1, u + 2);
    BARRIER(); WAIT_LGKM0(); MFMA16(1, 0); BARRIER();
    LDB2(B1h, 1);
    if (u + 3 < ntiles) STAGE_A(1, 0, u + 3);
    BARRIER(); WAIT_LGKM0(); MFMA16(0, 1); BARRIER();
    if (u + 3 < ntiles) STAGE_A(1, 1, u + 3);
    BARRIER(); MFMA16(1, 1);
    WAIT_VM4(); BARRIER();
  }

#pragma unroll
  for (int mi = 0; mi < 8; ++mi)
#pragma unroll
    for (int ni = 0; ni < 4; ++ni)
#pragma unroll
      for (int r = 0; r < 4; ++r) {
        int row = m0 + wr * 128 + mi * 16 + lg * 4 + r;
        int col = n0 + wc * 64 + ni * 16 + lr;
        size_t idx = (size_t)row * N + col;
        C[idx] = f2bf(acc[mi][ni][r]);
      }
#undef STAGE_A
#undef STAGE_B
#undef LDA4
#undef LDB2
#undef MFMA16
}

// ---------------- GEMM 256x256 8-phase, fused-SwiGLU epilogue --------------
// Byte-identical to R12..R16. out = silu(gate) * (A*Bt^T), bf16.
__global__ __launch_bounds__(512, 2) void gemm256_swiglu_kernel(
    const ushort* __restrict__ A, const ushort* __restrict__ Bt,
    ushort* __restrict__ C, const ushort* __restrict__ gate,
    int M, int N, int K) {
  extern __shared__ ushort lds[];
  ushort* Al = lds;
  ushort* Bl = lds + 32768;
  const int t = threadIdx.x, l = t & 63, w = t >> 6;
  const int wr = w >> 2, wc = w & 3;
  const int lr = l & 15, lg = l >> 4;
  const int rhi = lr >> 3, rlo = lr & 7;
  const int srow = l >> 3, sg = (l & 7) ^ srow;

  const int nby = M >> 8;
  const int nwg = (N >> 8) * nby;
  const int cpx = nwg >> 3;
  const int bid = (int)blockIdx.x;
  const int swz = (bid & 7) * cpx + (bid >> 3);
  const int m0 = (swz % nby) << 8;
  const int n0 = (swz / nby) << 8;

  const int lof0 = rhi * 512 + rlo * 64 + ((0 + lg) ^ rlo) * 8;
  const int lof1 = rhi * 512 + rlo * 64 + ((4 + lg) ^ rlo) * 8;

  const f32x4 fz = {0.f, 0.f, 0.f, 0.f};
  f32x4 acc[8][4];
#pragma unroll
  for (int i = 0; i < 8; ++i)
#pragma unroll
    for (int j = 0; j < 4; ++j) acc[i][j] = fz;
  bf16x8 a[8][2];
  bf16x8 bq[2][2];

  const ushort* Asrc = A + (size_t)(m0 + w * 8 + srow) * K + sg * 8;
  const ushort* Bsrc = Bt + (size_t)(n0 + w * 8 + srow) * K + sg * 8;
  const size_t rK64 = (size_t)64 * K, rK128 = (size_t)128 * K;
  ushort* Adst = Al + w * 512;
  ushort* Bdst = Bl + w * 512;

#define STAGE_A(buf, half, tile) do {                                   \
    const ushort* s_ = Asrc + (size_t)(half) * rK128 + ((tile) << 6);   \
    ushort* d_ = Adst + (buf) * 16384 + (half) * 8192;                  \
    gload16(s_, d_);                                                    \
    gload16(s_ + rK64, d_ + 4096);                                      \
  } while (0)
#define STAGE_B(buf, half, tile) do {                                   \
    const ushort* s_ = Bsrc + (size_t)(half) * rK128 + ((tile) << 6);   \
    ushort* d_ = Bdst + (buf) * 16384 + (half) * 8192;                  \
    gload16(s_, d_);                                                    \
    gload16(s_ + rK64, d_ + 4096);                                      \
  } while (0)
#define LDA4(AH, QM) do {                                                   \
    _Pragma("unroll") for (int mi_ = 0; mi_ < 4; ++mi_) {                   \
      a[(QM) * 4 + mi_][0] =                                                \
          *(const bf16x8*)((AH) + ((QM) * 4 + mi_) * 1024 + lof0);          \
      a[(QM) * 4 + mi_][1] =                                                \
          *(const bf16x8*)((AH) + ((QM) * 4 + mi_) * 1024 + lof1);          \
    } } while (0)
#define LDB2(BH, NQ) do {                                                   \
    _Pragma("unroll") for (int nj_ = 0; nj_ < 2; ++nj_) {                   \
      bq[nj_][0] = *(const bf16x8*)((BH) + ((NQ) * 2 + nj_) * 1024 + lof0); \
      bq[nj_][1] = *(const bf16x8*)((BH) + ((NQ) * 2 + nj_) * 1024 + lof1); \
    } } while (0)
#define MFMA16(QM, QN)                                                      \
    __builtin_amdgcn_s_setprio(1);                                          \
    _Pragma("unroll") for (int mi_ = 0; mi_ < 4; ++mi_)                     \
    _Pragma("unroll") for (int nj_ = 0; nj_ < 2; ++nj_) {                   \
      acc[(QM) * 4 + mi_][(QN) * 2 + nj_] =                                 \
          __builtin_amdgcn_mfma_f32_16x16x32_bf16(                          \
              a[(QM) * 4 + mi_][0], bq[nj_][0],                             \
              acc[(QM) * 4 + mi_][(QN) * 2 + nj_], 0, 0, 0);                \
      acc[(QM) * 4 + mi_][(QN) * 2 + nj_] =                                 \
          __builtin_amdgcn_mfma_f32_16x16x32_bf16(                          \
              a[(QM) * 4 + mi_][1], bq[nj_][1],                             \
              acc[(QM) * 4 + mi_][(QN) * 2 + nj_], 0, 0, 0);                \
    }                                                                       \
    __builtin_amdgcn_s_setprio(0);

  const ushort* A0h = Al + wr * 8192;
  const ushort* A1h = A0h + 16384;
  const ushort* B0h = Bl + (wc >> 1) * 8192 + (wc & 1) * 4096;
  const ushort* B1h = B0h + 16384;

  const int ntiles = K >> 6, nIter = K >> 7;
  STAGE_A(0, 0, 0); STAGE_A(0, 1, 0); STAGE_B(0, 0, 0); STAGE_B(0, 1, 0);
  STAGE_A(1, 0, 1); STAGE_A(1, 1, 1);
  WAIT_VM4(); BARRIER();

  for (int it = 0; it < nIter; ++it) {
    const int u = it * 2;
    LDA4(A0h, 0); LDB2(B0h, 0);
    STAGE_B(1, 0, u + 1);
    BARRIER(); WAIT_LGKM0(); MFMA16(0, 0); BARRIER();
    LDA4(A0h, 1);
    STAGE_B(1, 1, u + 1);
    BARRIER(); WAIT_LGKM0(); MFMA16(1, 0); BARRIER();
    LDB2(B0h, 1);
    if (u + 2 < ntiles) STAGE_A(0, 0, u + 2);
    BARRIER(); WAIT_LGKM0(); MFMA16(0, 1); BARRIER();
    if (u + 2 < ntiles) STAGE_A(0, 1, u + 2);
    BARRIER(); MFMA16(1, 1);
    if (u + 2 < ntiles) { WAIT_VM4(); } else { WAIT_VM0(); }
    BARRIER();
    LDA4(A1h, 0); LDB2(B1h, 0);
    if (u + 2 < ntiles) STAGE_B(0, 0, u + 2);
    BARRIER(); WAIT_LGKM0(); MFMA16(0, 0); BARRIER();
    LDA4(A1h, 1);
    if (u + 2 < ntiles) STAGE_B(0, 1, u + 2);
    BARRIER(); WAIT_LGKM0(); MFMA16(1, 0); BARRIER();
    LDB2(B1h, 1);
    if (u + 3 < ntiles) STAGE_A(1, 0, u + 3);
    BARRIER(); WAIT_LGKM0(); MFMA16(0, 1); BARRIER();
    if (u + 3 < ntiles) STAGE_A(1, 1, u + 3);
    BARRIER(); MFMA16(1, 1);
    WAIT_VM4(); BARRIER();
  }

  // fused epilogue: out = silu(gate) * acc
#pragma unroll
  for (int mi = 0; mi < 8; ++mi)
#pragma unroll
    for (int ni = 0; ni < 4; ++ni)
#pragma unroll
      for (int r = 0; r < 4; ++r) {
        int row = m0 + wr * 128 + mi * 16 + lg * 4 + r;
        int col = n0 + wc * 64 + ni * 16 + lr;
        size_t idx = (size_t)row * N + col;
        float g = bf2f(gate[idx]);
        float s = g / (1.f + __expf(-g));
        C[idx] = f2bf(s * acc[mi][ni][r]);
      }
#undef STAGE_A
#undef STAGE_B
#undef LDA4
#undef LDB2
#undef MFMA16
}

// --------- RoPE + scatter qkv[T,6144] -> Qr[b,h,s,d] Kr[b,h,s,d] Vt[b,h,d,s]
__global__ __launch_bounds__(256) void rope_scatter_kernel(
    const ushort* __restrict__ qkv, const float2* __restrict__ tab,
    ushort* __restrict__ Qr, ushort* __restrict__ Kr, ushort* __restrict__ Vt) {
  __shared__ ushort vt[64][132];
  const int t = threadIdx.x, tt = blockIdx.x, h = blockIdx.y;  // h: 0..47
  const int row = t >> 2, c = (t & 3) * 16;
  const int tok = tt * 64 + row;
  const int b = tok >> 11, s = tok & 2047;
  const ushort* ip = qkv + (size_t)tok * 6144 + h * 128;
  union U { uint4 v; ushort us[8]; };
  U a0, a1, b0, b1;
  a0.v = *(const uint4*)(ip + c);      a1.v = *(const uint4*)(ip + c + 8);
  b0.v = *(const uint4*)(ip + c + 64); b1.v = *(const uint4*)(ip + c + 72);
  if (h < 40) {  // q or k head: NeoX rope on pairs (i, i+64)
    U o0, o1, o2, o3;
#pragma unroll
    for (int j = 0; j < 8; ++j) {
      float2 cs = tab[s * 64 + c + j];
      float x1 = bf2f(a0.us[j]), x2 = bf2f(b0.us[j]);
      o0.us[j] = f2bf(x1 * cs.x - x2 * cs.y);
      o2.us[j] = f2bf(x2 * cs.x + x1 * cs.y);
    }
#pragma unroll
    for (int j = 0; j < 8; ++j) {
      float2 cs = tab[s * 64 + c + 8 + j];
      float x1 = bf2f(a1.us[j]), x2 = bf2f(b1.us[j]);
      o1.us[j] = f2bf(x1 * cs.x - x2 * cs.y);
      o3.us[j] = f2bf(x2 * cs.x + x1 * cs.y);
    }
    ushort* base;
    if (h < 32) base = Qr + ((size_t)((b * 32 + h) * 2048 + s)) * 128;
    else        base = Kr + ((size_t)((b * 8 + (h - 32)) * 2048 + s)) * 128;
    *(uint4*)(base + c)      = o0.v; *(uint4*)(base + c + 8)  = o1.v;
    *(uint4*)(base + c + 64) = o2.v; *(uint4*)(base + c + 72) = o3.v;
  } else {  // v head: LDS transpose -> Vt[b,hv,d,s]
    const int hv = h - 40;
#pragma unroll
    for (int j = 0; j < 8; ++j) {
      vt[row][c + j]      = a0.us[j]; vt[row][c + 8 + j]  = a1.us[j];
      vt[row][c + 64 + j] = b0.us[j]; vt[row][c + 72 + j] = b1.us[j];
    }
    __syncthreads();
    const int d = t >> 1, s0 = (t & 1) * 32, sb = (tt & 31) * 64;
    U w0, w1, w2, w3;
#pragma unroll
    for (int j = 0; j < 8; ++j) {
      w0.us[j] = vt[s0 + j][d];      w1.us[j] = vt[s0 + 8 + j][d];
      w2.us[j] = vt[s0 + 16 + j][d]; w3.us[j] = vt[s0 + 24 + j][d];
    }
    ushort* vb = Vt + ((size_t)((b * 8 + hv) * 128 + d)) * 2048 + sb + s0;
    *(uint4*)(vb) = w0.v;      *(uint4*)(vb + 8) = w1.v;
    *(uint4*)(vb + 16) = w2.v; *(uint4*)(vb + 24) = w3.v;
  }
}

// ------------- flash attention + hidden weight transposes ------------------
// Byte-identical to R13..R16 attn_tc.
__global__ __launch_bounds__(512) void attn_tc_kernel(
    const ushort* __restrict__ Q, const ushort* __restrict__ K,
    const ushort* __restrict__ V, ushort* __restrict__ O,
    const float* t1in, ushort* t1out, int t1ld, int t1off, int t1R, int t1ntx, int t1n,
    const float* t2in, ushort* t2out, int t2ld, int t2off, int t2R, int t2ntx, int t2n,
    const float* t3in, ushort* t3out, int t3ld, int t3off, int t3R, int t3ntx, int t3n) {
  extern __shared__ ushort sm[];
  const int bid = (int)blockIdx.x;
  const int t = threadIdx.x;
  if (bid >= 1024) {                      // transpose blocks
    int tb = bid - 1024;
    if (tb < t1n) {
      transpose512(t1in, t1out, t1ld, t1off, t1R, t1ntx, tb, sm, t);
    } else if (tb < t1n + t2n) {
      transpose512(t2in, t2out, t2ld, t2off, t2R, t2ntx, tb - t1n, sm, t);
    } else {
      transpose512(t3in, t3out, t3ld, t3off, t3R, t3ntx, tb - t1n - t2n, sm, t);
    }
    return;
  }
  const int qb = bid & 15, h = (bid >> 4) & 31, b = bid >> 9;

  ushort* Kl = sm;           // [2][64 s][128 d]
  ushort* Vl = sm + 16384;   // [2][128 d][64 s]
  ushort* Pl = sm + 32768;   // [128][64]
  const int l = t & 63, w = t >> 6;   // w: 0..7
  const int lr = l & 15, lg = l >> 4;
  const int hkv = h >> 2;
  const f32x4 fzero = {0.f, 0.f, 0.f, 0.f};

  const int rm = lr & 7;
  int ksw[4], vsw[2];
#pragma unroll
  for (int ks = 0; ks < 4; ++ks) ksw[ks] = ((ks * 4 + lg) ^ rm) * 8;
  vsw[0] = (lg ^ rm) * 8;
  vsw[1] = ((4 + lg) ^ rm) * 8;
  const int kcol = ((t & 15) ^ ((t >> 4) & 7)) * 8;   // staging src swizzle
  const int vcol = ((t & 7) ^ ((t >> 3) & 7)) * 8;

  const float qscale = 0.08838834764831845f * 1.4426950408889634f;
  const ushort* qp =
      Q + ((size_t)((b * 32 + h) * 2048 + qb * 128 + w * 16 + lr)) * 128 + lg * 8;
  bf16x8 qf[4];
#pragma unroll
  for (int ks = 0; ks < 4; ++ks) {
    bf16x8 raw = *(const bf16x8*)(qp + ks * 32);
#pragma unroll
    for (int j = 0; j < 8; ++j)
      qf[ks][j] = (short)f2bf(bf2f((ushort)raw[j]) * qscale);
  }
  bf16x8 ones;
#pragma unroll
  for (int j = 0; j < 8; ++j) ones[j] = (short)0x3F80;
  WAIT_VM0();

  const ushort* kg = K + ((size_t)(b * 8 + hkv)) * 2048 * 128;
  const ushort* vg = V + ((size_t)(b * 8 + hkv)) * 128 * 2048;

#define STAGE_KV(buf, s0_) do {                                              \
    _Pragma("unroll") for (int i_ = 0; i_ < 2; ++i_)                         \
      gload16(kg + (size_t)((s0_) + i_ * 32 + (t >> 4)) * 128 + kcol,        \
              (char*)Kl + (buf) * 16384 + i_ * 8192 + t * 16);               \
    _Pragma("unroll") for (int i_ = 0; i_ < 2; ++i_)                         \
      gload16(vg + (size_t)(i_ * 64 + (t >> 3)) * 2048 + (s0_) + vcol,       \
              (char*)Vl + (buf) * 16384 + i_ * 8192 + t * 16);               \
  } while (0)

  f32x4 accO[8];
#pragma unroll
  for (int i = 0; i < 8; ++i) accO[i] = fzero;
  float m_r[4] = {-1e30f, -1e30f, -1e30f, -1e30f};
  float l_r[4] = {0.f, 0.f, 0.f, 0.f};
  const int qrow = qb * 128 + w * 16 + lg * 4;
  const int wrow0 = qb * 128 + w * 16;
  const int jend = 2 * qb + 1;

  STAGE_KV(0, 0);
  for (int j = 0; j <= jend; ++j) {
    if (j < jend) { STAGE_KV((j + 1) & 1, (j + 1) * 64); WAIT_VM4(); }
    else          { WAIT_VM0(); }
    BARRIER();
    const ushort* Kb = Kl + (j & 1) * 8192;
    const ushort* Vb = Vl + (j & 1) * 8192;

    f32x4 sc[4];
#pragma unroll
    for (int ni = 0; ni < 4; ++ni) sc[ni] = fzero;
    __builtin_amdgcn_s_setprio(1);
#pragma unroll
    for (int ni = 0; ni < 4; ++ni)
#pragma unroll
      for (int ks = 0; ks < 4; ++ks) {
        bf16x8 kf = *(const bf16x8*)(Kb + (ni * 16 + lr) * 128 + ksw[ks]);
        sc[ni] = __builtin_amdgcn_mfma_f32_16x16x32_bf16(qf[ks], kf, sc[ni], 0, 0, 0);
      }
    __builtin_amdgcn_s_setprio(0);
    if (j * 64 + 63 > wrow0) {
#pragma unroll
      for (int ni = 0; ni < 4; ++ni)
#pragma unroll
        for (int r = 0; r < 4; ++r)
          if (j * 64 + ni * 16 + lr > qrow + r) sc[ni][r] = -1e30f;
    }
    float mx[4];
#pragma unroll
    for (int r = 0; r < 4; ++r) {
      float v = fmaxf(fmaxf(sc[0][r], sc[1][r]), fmaxf(sc[2][r], sc[3][r]));
#pragma unroll
      for (int m = 8; m; m >>= 1) v = fmaxf(v, __shfl_xor(v, m));
      mx[r] = v;
    }
    bool ok = mx[0] <= m_r[0] + 8.f && mx[1] <= m_r[1] + 8.f &&
              mx[2] <= m_r[2] + 8.f && mx[3] <= m_r[3] + 8.f;
    if (!__all(ok)) {
#pragma unroll
      for (int r = 0; r < 4; ++r) {
        float mnew = fmaxf(m_r[r], mx[r]);
        float fsc = exp2f(m_r[r] - mnew);
        l_r[r] *= fsc;
        m_r[r] = mnew;
#pragma unroll
        for (int i = 0; i < 8; ++i) accO[i][r] *= fsc;
      }
    }
#pragma unroll
    for (int ni = 0; ni < 4; ++ni)
#pragma unroll
      for (int r = 0; r < 4; ++r) {
        int prow = w * 16 + lg * 4 + r;
        int slot = (ni * 2 + (lr >> 3)) ^ (prow & 7);
        Pl[prow * 64 + slot * 8 + rm] = f2bf(exp2f(sc[ni][r] - m_r[r]));
      }
    WAIT_LGKM0();
    f32x4 accL = fzero;
    __builtin_amdgcn_s_setprio(1);
#pragma unroll
    for (int ks = 0; ks < 2; ++ks) {
      bf16x8 pf = *(const bf16x8*)(Pl + (w * 16 + lr) * 64 + vsw[ks]);
#pragma unroll
      for (int nf = 0; nf < 8; ++nf) {
        bf16x8 vf = *(const bf16x8*)(Vb + (nf * 16 + lr) * 64 + vsw[ks]);
        accO[nf] = __builtin_amdgcn_mfma_f32_16x16x32_bf16(pf, vf, accO[nf], 0, 0, 0);
      }
      accL = __builtin_amdgcn_mfma_f32_16x16x32_bf16(pf, ones, accL, 0, 0, 0);
    }
    __builtin_amdgcn_s_setprio(0);
#pragma unroll
    for (int r = 0; r < 4; ++r) l_r[r] += accL[r];
    BARRIER();
  }
#undef STAGE_KV
  float invl[4];
#pragma unroll
  for (int r = 0; r < 4; ++r) invl[r] = 1.f / l_r[r];
#pragma unroll
  for (int nf = 0; nf < 8; ++nf)
#pragma unroll
    for (int r = 0; r < 4; ++r) {
      int q = qb * 128 + w * 16 + lg * 4 + r;
      int d = nf * 16 + lr;
      O[((size_t)(b * 2048 + q)) * 4096 + h * 128 + d] = f2bf(accO[nf][r] * invl[r]);
    }
}

// ------------------------------ launcher -----------------------------------
#define OFF_A     ((size_t)0)           // qkvb | W3 | act
#define OFF_B     ((size_t)90177536)    // tab | W4
#define OFF_D     ((size_t)180355072)   // W1 | Qr/Kr/Vt | gate
#define OFF_C     ((size_t)270532608)   // W2 | W5
#define OFF_E     ((size_t)360710144)   // xn | attnb | xn
#define OFF_TAB   (OFF_B)
#define OFF_QR    (OFF_D + 1048576)
#define OFF_KR    (OFF_D + 34603008)
#define OFF_VT    (OFF_D + 42991616)
#define WS_NEED   ((size_t)416284672)

extern "C" void kernel_launch(void* const* d_in, const int* in_sizes, int n_in,
                              void* d_out, int out_size, void* d_ws,
                              size_t ws_size, hipStream_t stream) {
  (void)in_sizes; (void)n_in; (void)out_size;
  if (ws_size < WS_NEED) return;
  const float* hs     = (const float*)d_in[0];
  const int*   pos    = (const int*)d_in[1];
  const float* w_qkv  = (const float*)d_in[2];
  const float* w_o    = (const float*)d_in[3];
  const float* w_gu   = (const float*)d_in[4];
  const float* w_down = (const float*)d_in[5];
  const float* ln1    = (const float*)d_in[6];
  const float* ln2    = (const float*)d_in[7];
  float* out = (float*)d_out;
  float* h1  = (float*)d_out;          // residual stream lives in d_out
  char* ws = (char*)d_ws;

  ushort* qkvb  = (ushort*)(ws + OFF_A);
  ushort* W3    = (ushort*)(ws + OFF_A);
  ushort* act   = (ushort*)(ws + OFF_A);
  float2* tab   = (float2*)(ws + OFF_TAB);
  ushort* W4    = (ushort*)(ws + OFF_B);
  ushort* W1    = (ushort*)(ws + OFF_D);
  ushort* gate  = (ushort*)(ws + OFF_D);
  ushort* Qr    = (ushort*)(ws + OFF_QR);
  ushort* Kr    = (ushort*)(ws + OFF_KR);
  ushort* Vt    = (ushort*)(ws + OFF_VT);
  ushort* W2    = (ushort*)(ws + OFF_C);
  ushort* W5    = (ushort*)(ws + OFF_C);
  ushort* xn    = (ushort*)(ws + OFF_E);
  ushort* attnb = (ushort*)(ws + OFF_E);

  auto kb = gemm256_kernel<ushort, false>;
  auto kf = gemm256_kernel<float, true>;
  hipFuncSetAttribute((const void*)kb, hipFuncAttributeMaxDynamicSharedMemorySize, 131072);
  hipFuncSetAttribute((const void*)kf, hipFuncAttributeMaxDynamicSharedMemorySize, 131072);
  hipFuncSetAttribute((const void*)gemm256_tc_kernel, hipFuncAttributeMaxDynamicSharedMemorySize, 131072);
  hipFuncSetAttribute((const void*)gemm256_swiglu_kernel, hipFuncAttributeMaxDynamicSharedMemorySize, 131072);
  hipFuncSetAttribute((const void*)attn_tc_kernel, hipFuncAttributeMaxDynamicSharedMemorySize, 81920);

  // s1: fused rmsnorm1 -> xn(E), w_qkv -> W1(D), rope table -> tab(B)
  pre_kernel<<<4096 + 3072 + 256, 512, 0, stream>>>(
      hs, ln1, xn, w_qkv, W1, pos, tab);
  // s3: qkv GEMM -> qkvb(A) + hidden transpose (w_o -> W2(C)) in idle tail
  gemm256_tc_kernel<<<384 + 2048, 512, 131072, stream>>>(
      xn, W1, qkvb, 4096, 6144, 4096,
      w_o, W2, 4096, 0, 4096, 64);
  // s4: rope scatter -> Qr/Kr/Vt (D, over W1)
  rope_scatter_kernel<<<dim3(64, 48), 256, 0, stream>>>(qkvb, tab, Qr, Kr, Vt);
  // s5: attn -> attnb(E) + hidden transposes (w_gu p1->W3(A), p2->W4(B))
  attn_tc_kernel<<<1024 + 5504 + 5504, 512, 81920, stream>>>(
      Qr, Kr, Vt, attnb,
      w_gu, W3, 22016, 0,     4096, 64, 5504,
      w_gu, W4, 22016, 11008, 4096, 64, 5504,
      w_o,  W2, 4096,  0,     4096, 64, 0);
  // s7: o-proj (residual hs) -> h1 (= d_out)
  gemm256_kernel<float, true><<<256, 512, 131072, stream>>>(
      attnb, W2, h1, hs, 4096, 4096, 4096);
  // s8: rmsnorm2 -> xn(E, over attnb), 512-thread variant
  rmsnorm512_kernel<<<4096, 512, 0, stream>>>(h1, ln2, xn);
  // s9: gate GEMM -> gate(D) + hidden transpose (w_down -> W5(C, over W2))
  gemm256_tc_kernel<<<688 + 5504, 512, 131072, stream>>>(
      xn, W3, gate, 4096, 11008, 4096,
      w_down, W5, 4096, 0, 11008, 172);
  // s10: up GEMM + fused SwiGLU -> act(A, over W3)
  gemm256_swiglu_kernel<<<688, 512, 131072, stream>>>(
      xn, W4, act, gate, 4096, 11008, 4096);
  // s12: down GEMM, residual h1 (= d_out), same-index in-place write
  gemm256_kernel<float, true><<<256, 512, 131072, stream>>>(
      act, W5, out, h1, 4096, 4096, 11008);
}